// Round 9
// baseline (125.786 us; speedup 1.0000x reference)
//
#include <hip/hip_runtime.h>
#include <math.h>

#define DET 512
#define NA  180
#define OUT 362   // floor(sqrt(512^2/2))
#define RAD 181   // OUT/2
#define OUTSQ (OUT * OUT)
#define NB  4     // batch size (fixed: x is (4,1,512,180))

#define NSPLIT 15       // angle partitions (all 4 b's fused per block)
#define APB    12       // angles per block (NA / NSPLIT)

// ---------------------------------------------------------------------------
// Compile-time tables / weights.
// ---------------------------------------------------------------------------
constexpr double PI_D = 3.14159265358979323846;

constexpr double tsin(double x) {  // |x| <= pi/4
    double x2 = x * x;
    return x * (1.0 + x2 * (-1.0/6 + x2 * (1.0/120 + x2 * (-1.0/5040 +
               x2 * (1.0/362880 + x2 * (-1.0/39916800))))));
}
constexpr double tcos(double x) {  // |x| <= pi/4
    double x2 = x * x;
    return 1.0 + x2 * (-0.5 + x2 * (1.0/24 + x2 * (-1.0/720 +
               x2 * (1.0/40320 + x2 * (-1.0/3628800)))));
}

struct Trig { float c[NA]; float s[NA]; };
constexpr Trig make_trig() {
    Trig t{};
    constexpr double r = PI_D / 180.0;
    for (int k = 0; k < NA; ++k) {
        double c, s;
        if (k <= 45)       { c =  tcos(k * r);          s =  tsin(k * r); }
        else if (k <= 90)  { c =  tsin((90 - k) * r);   s =  tcos((90 - k) * r); }
        else if (k <= 135) { c = -tsin((k - 90) * r);   s =  tcos((k - 90) * r); }
        else               { c = -tcos((180 - k) * r);  s =  tsin((180 - k) * r); }
        t.c[k] = (float)c; t.s[k] = (float)s;
    }
    return t;
}
__device__ constexpr Trig TRIG = make_trig();

// Ramp weight for odd offset m: w(m) = -2/(pi*m)^2; 0 outside [-511,511] or
// even m.  ONLY used in constexpr context so it folds to a 32-bit literal
// (R4 lesson: runtime eval = f64 VALU storm, 90 us).
__host__ __device__ constexpr float rampw0(int m) {
    int a = m < 0 ? -m : m;
    if (a > 511 || (a & 1) == 0) return 0.0f;
    double md = (double)a;
    return (float)(-2.0 / (PI_D * PI_D * md * md));
}

// One tap: v = p[R] feeds the 4 accumulators with compile-time weights.
template<int R>
__device__ __forceinline__ void tap(const float* __restrict__ p,
        float& a0, float& a1, float& a2, float& a3) {
    const float v = p[R];
    if constexpr (rampw0(R)      != 0.0f) a0 = fmaf(rampw0(R),      v, a0);
    if constexpr (rampw0(R - 32) != 0.0f) a1 = fmaf(rampw0(R - 32), v, a1);
    if constexpr (rampw0(R - 64) != 0.0f) a2 = fmaf(rampw0(R - 64), v, a2);
    if constexpr (rampw0(R - 96) != 0.0f) a3 = fmaf(rampw0(R - 96), v, a3);
}

// Straight-line sweep over odd offsets R, R+2, ..., REND.
template<int R, int REND>
__device__ __forceinline__ void sweep(const float* __restrict__ p,
        float& a0, float& a1, float& a2, float& a3) {
    if constexpr (R <= REND) {
        tap<R>(p, a0, a1, a2, a3);
        sweep<R + 2, REND>(p, a0, a1, a2, a3);
    }
}

// ---------------------------------------------------------------------------
// Kernel 1: ramp filter (R5-proven half-split structure), store remapped to
// the batch-interleaved ft[a][d][b] layout for the fused backprojector.
// ---------------------------------------------------------------------------
__global__ __launch_bounds__(256) void ramp_filter_kernel(
        const float* __restrict__ x, float* __restrict__ ft) {
    const int a   = blockIdx.x;
    const int b   = blockIdx.y;
    const int tid = threadIdx.x;        // 0..255
    const int t    = tid & 127;         // output-thread id
    const int half = tid >> 7;          // window half
    const int q = (t & 31) + 128 * (t >> 5);   // base output (covers all 512)

    __shared__ float xs[3 * DET];       // [0,512) zeros | data | [1024,1536) zeros
    __shared__ float red[4 * 128];      // half-1 partial accumulators

    xs[tid]        = 0.0f;
    xs[256 + tid]  = 0.0f;
    xs[1024 + tid] = 0.0f;
    xs[1280 + tid] = 0.0f;
    xs[512 + tid]  = x[(b * DET + tid) * NA + a];
    xs[768 + tid]  = x[(b * DET + 256 + tid) * NA + a];
    __syncthreads();

    const float* p = xs + 512 + q;
    float a0 = 0.0f, a1 = 0.0f, a2 = 0.0f, a3 = 0.0f;

    if (half == 0) {
        a0 = 0.5f * p[0];               // center taps, once
        a1 = 0.5f * p[32];
        a2 = 0.5f * p[64];
        a3 = 0.5f * p[96];
        sweep<-511, 47>(p, a0, a1, a2, a3);
    } else {
        sweep<49, 607>(p, a0, a1, a2, a3);
        red[      t] = a0;
        red[128 + t] = a1;
        red[256 + t] = a2;
        red[384 + t] = a3;
    }
    __syncthreads();

    if (half == 0) {
        // batch-interleaved store: ft[(a*DET + d)*NB + b]
        float* ob = ft + ((size_t)a * DET + q) * NB + b;
        ob[0]           = a0 + red[      t];
        ob[32 * NB]     = a1 + red[128 + t];
        ob[64 * NB]     = a2 + red[256 + t];
        ob[96 * NB]     = a3 + red[384 + t];
    }
}

// ---------------------------------------------------------------------------
// Kernel 2: backprojection, batch-of-4 fused, NO LDS (L1/L2-direct).
// ft (1.47 MB) is fully L2-resident; a 32x32 tile's per-angle window is only
// ~34-47 quads (~600 B) -> L1-dominated.  Staging it through LDS was pure
// overhead (R6/R7/R8: 45-51 us, issue efficiency ~40%, barrier+latency
// bound at ~2 resident blocks/CU).  This version: 2 global_load_dwordx4 per
// position (one address, second folds offset:16), guard via multiply-mask
// (same FMA count as an add), zero barriers, zero LDS -> occupancy limited
// only by threads/VGPR.
// ---------------------------------------------------------------------------
__device__ __forceinline__ void acc4g(float4& acc,
        const float4* __restrict__ L, float pos) {
    int   i0 = (int)pos;                 // pos >= 0 here -> trunc == floor
    i0 = min(i0, DET - 2);               // keep L[i0+1] in-bounds
    float fr = pos - (float)i0;          // pos==511.0: i0=510, fr=1.0 -> g[511]
    float msk = pos <= (float)(DET - 1) ? 1.0f : 0.0f;   // fill=0 outside
    float4 g0 = L[i0];
    float4 g1 = L[i0 + 1];
    acc.x = fmaf(msk, fmaf(fr, g1.x - g0.x, g0.x), acc.x);
    acc.y = fmaf(msk, fmaf(fr, g1.y - g0.y, g0.y), acc.y);
    acc.z = fmaf(msk, fmaf(fr, g1.z - g0.z, g0.z), acc.z);
    acc.w = fmaf(msk, fmaf(fr, g1.w - g0.w, g0.w), acc.w);
}

__global__ __launch_bounds__(256) void backproject_kernel(
        const float4* __restrict__ ftq, float* __restrict__ out) {
    const int sp = blockIdx.z;               // angle partition (b's fused)
    const int r0 = blockIdx.y * 32;
    const int c0 = blockIdx.x * 32;
    const int tid = threadIdx.x;
    const int tx = tid & 15;
    const int ty = tid >> 4;

    // clamp base coordinate for guard pixels (r/c >= OUT); stores guarded.
    const float xpr = (float)(min(r0 + ty, OUT - 1) - RAD);   // row coord
    const float ypr = (float)(min(c0 + tx, OUT - 1) - RAD);   // col coord

    float4 A00 = {0,0,0,0}, A01 = {0,0,0,0}, A10 = {0,0,0,0}, A11 = {0,0,0,0};

    const int ab = sp * APB;
    #pragma unroll 2
    for (int i = 0; i < APB; ++i) {
        const float cv = TRIG.c[ab + i];
        const float sv = TRIG.s[ab + i];
        const float4* L = ftq + (size_t)(ab + i) * DET;
        // pos = ypr*cos - xpr*sin + det/2
        float p00 = fmaf(ypr, cv, fmaf(xpr, -sv, 256.0f));
        float p01 = fmaf(16.0f, cv, p00);       // col+16
        float p10 = fmaf(-16.0f, sv, p00);      // row+16
        float p11 = fmaf(-16.0f, sv, p01);      // row+16, col+16
        acc4g(A00, L, p00);
        acc4g(A01, L, p01);
        acc4g(A10, L, p10);
        acc4g(A11, L, p11);
    }

    const float scale = (float)(PI_D / (2.0 * NA));
    const int r = r0 + ty;
    const int c = c0 + tx;

#define EMIT(ACC, RR, CC)                                          \
    if ((RR) < OUT && (CC) < OUT) {                                \
        const int off = (RR) * OUT + (CC);                         \
        atomicAdd(out + off,             (ACC).x * scale);         \
        atomicAdd(out + OUTSQ + off,     (ACC).y * scale);         \
        atomicAdd(out + 2 * OUTSQ + off, (ACC).z * scale);         \
        atomicAdd(out + 3 * OUTSQ + off, (ACC).w * scale);         \
    }
    EMIT(A00, r, c);
    EMIT(A01, r, c + 16);
    EMIT(A10, r + 16, c);
    EMIT(A11, r + 16, c + 16);
#undef EMIT
}

extern "C" void kernel_launch(void* const* d_in, const int* in_sizes, int n_in,
                              void* d_out, int out_size, void* d_ws, size_t ws_size,
                              hipStream_t stream) {
    const float* x = (const float*)d_in[0];
    float* ft  = (float*)d_ws;     // NA*DET*NB*4 = 1.47 MB scratch, b-interleaved
    float* out = (float*)d_out;

    const int B = in_sizes[0] / (DET * NA);   // 4 (problem is fixed at B=4)

    hipMemsetAsync(out, 0, (size_t)out_size * sizeof(float), stream);
    ramp_filter_kernel<<<dim3(NA, B), 256, 0, stream>>>(x, ft);
    backproject_kernel<<<dim3((OUT + 31) / 32, (OUT + 31) / 32, NSPLIT),
                         256, 0, stream>>>((const float4*)ft, out);
}